// Round 1
// baseline (150.396 us; speedup 1.0000x reference)
//
#include <hip/hip_runtime.h>
#include <math.h>

// Problem constants
#define B_     4
#define N_     2048
#define H_     256
#define ROWS   8192    // B_*N_
#define EPS_   1e-8f
#define REGW   1e-5f
#define OUT_MAIN (ROWS*H_)   // 2097152

static __device__ __forceinline__ float elu1(float x) {
    return x > 0.f ? x + 1.f : __expf(x);
}

// fp32 pair -> packed bf16x2 (RNE)
static __device__ __forceinline__ unsigned pack_bf16x2(float a, float b) {
    unsigned ua = __float_as_uint(a), ub = __float_as_uint(b);
    ua = (ua + 0x7FFFu + ((ua >> 16) & 1u)) >> 16;
    ub = (ub + 0x7FFFu + ((ub >> 16) & 1u)) & 0xFFFF0000u;
    return ua | ub;
}
// packed bf16x2 -> fp32 pair (exact)
static __device__ __forceinline__ float2 unpack_bf16x2(unsigned u) {
    return make_float2(__uint_as_float(u << 16), __uint_as_float(u & 0xFFFF0000u));
}

// stage + transpose a 256-row w_high chunk [256][24] -> dst[k*260 + j]
static __device__ __forceinline__ void stage_whT(
    const float* __restrict__ wsrc, float* __restrict__ dst, int t)
{
#pragma unroll
    for (int i = 0; i < 6; i++) {
        int g = t + i * 256;
        float4 v4 = *(const float4*)(wsrc + g * 4);
        int e = g * 4, j = e / 24, k = e - j * 24;
        dst[(k + 0) * 260 + j] = v4.x;
        dst[(k + 1) * 260 + j] = v4.y;
        dst[(k + 2) * 260 + j] = v4.z;
        dst[(k + 3) * 260 + j] = v4.w;
    }
}

// ---------------------------------------------------------------------------
// ka_fused: 512 blocks x 256 thr; block = 16 rows. (unchanged)
// ---------------------------------------------------------------------------
template<int MODE>  // 1 = k (elu + z), 2 = v (raw)
static __device__ __forceinline__ void chunk_compute(
    const float* __restrict__ buf, const float* __restrict__ qlT,
    const float* __restrict__ b_high, size_t rowbase,
    int wv, int c, unsigned* __restrict__ outu, float* __restrict__ zg)
{
    const int chunk = (MODE == 1) ? 1 : 2;
    float4 bh4 = *(const float4*)(b_high + chunk * 256 + c * 4);
    float4 a0 = bh4, a1 = bh4, a2 = bh4, a3 = bh4;
#pragma unroll
    for (int k = 0; k < 24; k++) {
        float4 w4 = *(const float4*)&buf[k * 260 + c * 4];
        float4 q4 = *(const float4*)&qlT[k * 16 + wv * 4];   // broadcast
        a0.x += q4.x * w4.x; a0.y += q4.x * w4.y; a0.z += q4.x * w4.z; a0.w += q4.x * w4.w;
        a1.x += q4.y * w4.x; a1.y += q4.y * w4.y; a1.z += q4.y * w4.z; a1.w += q4.y * w4.w;
        a2.x += q4.z * w4.x; a2.y += q4.z * w4.y; a2.z += q4.z * w4.z; a2.w += q4.z * w4.w;
        a3.x += q4.w * w4.x; a3.y += q4.w * w4.y; a3.z += q4.w * w4.z; a3.w += q4.w * w4.w;
    }
    const int h = c >> 4, dq = (c & 15) * 2;
    float4 aa[4] = {a0, a1, a2, a3};
    float zp[4];
#pragma unroll
    for (int rr = 0; rr < 4; rr++) {
        float4 a = aa[rr];
        if (MODE == 1) {
            a.x = elu1(a.x); a.y = elu1(a.y); a.z = elu1(a.z); a.w = elu1(a.w);
        }
        size_t row = rowbase + wv * 4 + rr;
        uint2 p;
        p.x = pack_bf16x2(a.x, a.y);
        p.y = pack_bf16x2(a.z, a.w);
        *(uint2*)(outu + ((size_t)h * ROWS + row) * 32 + dq) = p;
        if (MODE == 1) zp[rr] = a.x + a.y + a.z + a.w;
    }
    if (MODE == 1) {
#pragma unroll
        for (int rr = 0; rr < 4; rr++) {
            float s = zp[rr];
            s += __shfl_xor(s, 1, 16);
            s += __shfl_xor(s, 2, 16);
            s += __shfl_xor(s, 4, 16);
            s += __shfl_xor(s, 8, 16);
            zp[rr] = s;
        }
        if ((c & 15) == 0) {
#pragma unroll
            for (int rr = 0; rr < 4; rr++)
                zg[(rowbase + wv * 4 + rr) * 4 + h] = 1.f / (zp[rr] + EPS_);
        }
    }
}

__global__ __launch_bounds__(256) void ka_fused(
    const float* __restrict__ x, const float* __restrict__ w_low,
    const float* __restrict__ b_low, const float* __restrict__ w_high,
    const float* __restrict__ b_high, float* __restrict__ g_ql,
    unsigned* __restrict__ kf_u, unsigned* __restrict__ v_u,
    float* __restrict__ zg)
{
    __shared__ float bufA[24 * 260];
    __shared__ float bufB[24 * 260];
    __shared__ float qlT[24 * 16];

    const int t = threadIdx.x;
    const size_t rowbase = (size_t)blockIdx.x * 16;
    const int rb = t >> 4, c4 = t & 15;   // phase-b ids
    const int wv = t >> 6, c  = t & 63;   // phase-c ids

    // stage w_low [24][256] -> bufA[j*260+k] (straight copy)
#pragma unroll
    for (int i = 0; i < 6; i++) {
        int g = t + i * 256;
        int j = g >> 6, k = (g & 63) * 4;
        *(float4*)&bufA[j * 260 + k] = *(const float4*)(w_low + g * 4);
    }
    // stage + transpose w_high chunk1 (k-weights) -> bufB
    stage_whT(w_high + 6144, bufB, t);
    // x slice into registers (interleaved k-slices, coalesced)
    float4 xr[4];
#pragma unroll
    for (int i = 0; i < 4; i++)
        xr[i] = *(const float4*)(x + (rowbase + rb) * H_ + i * 64 + c4 * 4);
    __syncthreads();   // B1

    // phase b -> ql[24] (all lanes of a row-group hold the full vector)
    {
        float ql[24];
#pragma unroll
        for (int j = 0; j < 24; j++) {
            float s = 0.f;
#pragma unroll
            for (int i = 0; i < 4; i++) {
                float4 w4 = *(const float4*)&bufA[j * 260 + i * 64 + c4 * 4];
                s += xr[i].x * w4.x + xr[i].y * w4.y + xr[i].z * w4.z + xr[i].w * w4.w;
            }
            s += __shfl_xor(s, 1, 16);
            s += __shfl_xor(s, 2, 16);
            s += __shfl_xor(s, 4, 16);
            s += __shfl_xor(s, 8, 16);
            ql[j] = s + b_low[j];
        }
        // global ql col-major [k][row]: 64B runs per (k, rowgroup)
        size_t row = rowbase + rb;
        g_ql[(size_t)c4 * ROWS + row] = ql[c4];
        if (c4 < 8) g_ql[(size_t)(16 + c4) * ROWS + row] = ql[16 + c4];
        qlT[c4 * 16 + rb] = ql[c4];
        if (c4 < 8) qlT[(16 + c4) * 16 + rb] = ql[16 + c4];
    }
    __syncthreads();   // B2: qlT visible; bufA free

    stage_whT(w_high + 12288, bufA, t);     // v-weights -> bufA (overlaps kf)
    chunk_compute<1>(bufB, qlT, b_high, rowbase, wv, c, kf_u, zg);
    __syncthreads();   // B3

    chunk_compute<2>(bufA, qlT, b_high, rowbase, wv, c, v_u, zg);
}

// ---------------------------------------------------------------------------
// k2_kv (RESTRUCTURED): partial kv over 32-row chunks.
// Grid 1024 = b*256 + h*64 + ch.  LDS 2 x [32][68] f32 = 17.4 KB ->
// ~4 blocks/CU co-resident (16 waves/CU, 4 waves/SIMD) instead of the old
// 1 block/CU (69.6 KB LDS, 1 wave/SIMD, fully latency-exposed).
// ---------------------------------------------------------------------------
__global__ __launch_bounds__(256) void k2_kv(
    const unsigned* __restrict__ kfu, const unsigned* __restrict__ vu,
    float* __restrict__ kvp)
{
    __shared__ float kfs[32 * 68];
    __shared__ float vss[32 * 68];
    const int blk = blockIdx.x;
    const int b = blk >> 8, h = (blk >> 6) & 3, ch = blk & 63;
    const int t = threadIdx.x;
    const size_t base_u = ((size_t)h * ROWS + (size_t)b * N_ + ch * 32) * 32;
    // stage: 32 rows x 8 uint4 per array = 256 uint4 -> exactly 1 per thread
    {
        int r = t >> 3, q = t & 7;
        uint4 ku = *(const uint4*)(kfu + base_u + r * 32 + q * 4);
        uint4 vv4 = *(const uint4*)(vu + base_u + r * 32 + q * 4);
        float2 f0 = unpack_bf16x2(ku.x), f1 = unpack_bf16x2(ku.y);
        float2 f2 = unpack_bf16x2(ku.z), f3 = unpack_bf16x2(ku.w);
        *(float4*)&kfs[r * 68 + q * 8 + 0] = make_float4(f0.x, f0.y, f1.x, f1.y);
        *(float4*)&kfs[r * 68 + q * 8 + 4] = make_float4(f2.x, f2.y, f3.x, f3.y);
        f0 = unpack_bf16x2(vv4.x); f1 = unpack_bf16x2(vv4.y);
        f2 = unpack_bf16x2(vv4.z); f3 = unpack_bf16x2(vv4.w);
        *(float4*)&vss[r * 68 + q * 8 + 0] = make_float4(f0.x, f0.y, f1.x, f1.y);
        *(float4*)&vss[r * 68 + q * 8 + 4] = make_float4(f2.x, f2.y, f3.x, f3.y);
    }
    __syncthreads();
    const int d0 = (t >> 4) * 4, e0 = (t & 15) * 4;
    float4 a0 = {0,0,0,0}, a1 = {0,0,0,0}, a2 = {0,0,0,0}, a3 = {0,0,0,0};
#pragma unroll 4
    for (int i = 0; i < 32; i++) {
        float4 kk = *(const float4*)&kfs[i * 68 + d0];
        float4 v4 = *(const float4*)&vss[i * 68 + e0];
        a0.x += kk.x * v4.x; a0.y += kk.x * v4.y; a0.z += kk.x * v4.z; a0.w += kk.x * v4.w;
        a1.x += kk.y * v4.x; a1.y += kk.y * v4.y; a1.z += kk.y * v4.z; a1.w += kk.y * v4.w;
        a2.x += kk.z * v4.x; a2.y += kk.z * v4.y; a2.z += kk.z * v4.z; a2.w += kk.z * v4.w;
        a3.x += kk.w * v4.x; a3.y += kk.w * v4.y; a3.z += kk.w * v4.z; a3.w += kk.w * v4.w;
    }
    float* outp = kvp + (size_t)blk * 4096;
    *(float4*)(outp + (d0 + 0) * 64 + e0) = a0;
    *(float4*)(outp + (d0 + 1) * 64 + e0) = a1;
    *(float4*)(outp + (d0 + 2) * 64 + e0) = a2;
    *(float4*)(outp + (d0 + 3) * 64 + e0) = a3;
}

// ---------------------------------------------------------------------------
// k2b: reduce 64 partials -> kv[bh][d*64+e]; write constant reg-loss
// (softmax rows sum to 1 => mean|attn| == 1/N; adj_u/adj_v cannot change it).
// Grid 256 x 256.  Partial blk layout is now simply bh*64 + ch.
// ---------------------------------------------------------------------------
__global__ __launch_bounds__(256) void k2b_reduce(
    const float* __restrict__ kvp, float* __restrict__ kvg,
    float* __restrict__ out)
{
    const int blk = blockIdx.x, t = threadIdx.x;
    const int bh = blk >> 4;
    const int idx = (blk & 15) * 256 + t;
    const float* p = kvp + (size_t)bh * 64 * 4096 + idx;
    float s = 0.f;
#pragma unroll
    for (int c = 0; c < 64; c++)
        s += p[(size_t)c * 4096];
    kvg[(size_t)bh * 4096 + idx] = s;
    if (blk == 0 && t == 0)
        out[OUT_MAIN] = REGW / (float)N_;   // 4.8828125e-9
}

// ---------------------------------------------------------------------------
// k4_out: 512 blocks x 256 thr; block = 16 rows. (unchanged)
// ---------------------------------------------------------------------------
__global__ __launch_bounds__(256) void k4_out(
    const float* __restrict__ g_ql, const float* __restrict__ w_high,
    const float* __restrict__ b_high, const float* __restrict__ zg,
    const float* __restrict__ kvg,
    const float* __restrict__ w_out_low, const float* __restrict__ b_out_low,
    const float* __restrict__ w_out_high, const float* __restrict__ b_out_high,
    float* __restrict__ out)
{
    __shared__ float bufW[24 * 260];   // w_high q^T; rows 0..15 reused as lin
    __shared__ float qfs[4 * 1092];    // [h][row 16][stride 68]
    __shared__ float qlT[24 * 16];
    __shared__ float lows[16 * 8];
    __shared__ float zs[64];
    float* lin = bufW;                 // alias: lin[16][260]

    const int t = threadIdx.x, blk = blockIdx.x;
    const int rowbase = blk * 16;
    const int b = blk >> 7;
    const float* kvb = kvg + (size_t)b * 4 * 4096;

    stage_whT(w_high, bufW, t);            // q-weights
    // stage qlT: 384 entries with 256 threads
    {
        int k = t >> 4, r = t & 15;
        qlT[t] = g_ql[(size_t)k * ROWS + rowbase + r];
        if (t < 128) {
            int idx2 = 256 + t;
            int k2 = idx2 >> 4, r2 = idx2 & 15;
            qlT[idx2] = g_ql[(size_t)k2 * ROWS + rowbase + r2];
        }
    }
    if (t < 64) zs[t] = zg[(size_t)rowbase * 4 + t];
    __syncthreads();

    const int wv = t >> 6, c = t & 63;
    const int h = c >> 4, e4 = c & 15;

    // phase 1: recompute qf rows wv*4..+3, cols j = c*4..+3 -> qfs[h][row][dl]
    {
        float4 bh4 = *(const float4*)(b_high + c * 4);
        float4 a0 = bh4, a1 = bh4, a2 = bh4, a3 = bh4;
#pragma unroll
        for (int k = 0; k < 24; k++) {
            float4 w4 = *(const float4*)&bufW[k * 260 + c * 4];
            float4 q4 = *(const float4*)&qlT[k * 16 + wv * 4];
            a0.x += q4.x * w4.x; a0.y += q4.x * w4.y; a0.z += q4.x * w4.z; a0.w += q4.x * w4.w;
            a1.x += q4.y * w4.x; a1.y += q4.y * w4.y; a1.z += q4.y * w4.z; a1.w += q4.y * w4.w;
            a2.x += q4.z * w4.x; a2.y += q4.z * w4.y; a2.z += q4.z * w4.z; a2.w += q4.z * w4.w;
            a3.x += q4.w * w4.x; a3.y += q4.w * w4.y; a3.z += q4.w * w4.z; a3.w += q4.w * w4.w;
        }
        float4 aa[4] = {a0, a1, a2, a3};
#pragma unroll
        for (int rr = 0; rr < 4; rr++) {
            float4 a = aa[rr];
            a.x = elu1(a.x); a.y = elu1(a.y); a.z = elu1(a.z); a.w = elu1(a.w);
            *(float4*)&qfs[h * 1092 + (wv * 4 + rr) * 68 + e4 * 4] = a;
        }
    }
    __syncthreads();   // qfs ready; bufW dead -> lin may be written

    // phase 2: lin[row][c*4..+3] = z * sum_d qf[row][h*64+d] * kv[h][d][e]
    {
        float4 acc[4] = {{0,0,0,0},{0,0,0,0},{0,0,0,0},{0,0,0,0}};
        const float* kvh = kvb + h * 4096 + e4 * 4;
        const float* qrow = &qfs[h * 1092 + (wv * 4) * 68];
#pragma unroll
        for (int d4 = 0; d4 < 16; d4++) {
            float4 k0 = *(const float4*)(kvh + (d4 * 4 + 0) * 64);
            float4 k1 = *(const float4*)(kvh + (d4 * 4 + 1) * 64);
            float4 k2 = *(const float4*)(kvh + (d4 * 4 + 2) * 64);
            float4 k3 = *(const float4*)(kvh + (d4 * 4 + 3) * 64);
#pragma unroll
            for (int rr = 0; rr < 4; rr++) {
                float4 qa = *(const float4*)(qrow + rr * 68 + d4 * 4);
                acc[rr].x += qa.x * k0.x + qa.y * k1.x + qa.z * k2.x + qa.w * k3.x;
                acc[rr].y += qa.x * k0.y + qa.y * k1.y + qa.z * k2.y + qa.w * k3.y;
                acc[rr].z += qa.x * k0.z + qa.y * k1.z + qa.z * k2.z + qa.w * k3.z;
                acc[rr].w += qa.x * k0.w + qa.y * k1.w + qa.z * k2.w + qa.w * k3.w;
            }
        }
#pragma unroll
        for (int rr = 0; rr < 4; rr++) {
            float zv = zs[(wv * 4 + rr) * 4 + h];
            *(float4*)&lin[(wv * 4 + rr) * 260 + c * 4] =
                make_float4(acc[rr].x * zv, acc[rr].y * zv,
                            acc[rr].z * zv, acc[rr].w * zv);
        }
    }
    __syncthreads();

    // phase 3: low projection (128 threads; 8-lane broadcast reads)
    if (t < 128) {
        int rr = t >> 3, j = t & 7;
        float a = b_out_low[j];
        const float4* wj = (const float4*)(w_out_low + j * H_);
#pragma unroll
        for (int kq = 0; kq < 64; kq++) {
            float4 l4 = *(const float4*)&lin[rr * 260 + kq * 4];
            float4 w4 = wj[kq];
            a += l4.x * w4.x + l4.y * w4.y + l4.z * w4.z + l4.w * w4.w;
        }
        lows[rr * 8 + j] = a;
    }
    __syncthreads();

    // phase 4: high projection, coalesced f4 stores
    {
        int rr = t >> 4, ig = t & 15;
        float l[8];
#pragma unroll
        for (int j = 0; j < 8; j++) l[j] = lows[rr * 8 + j];
        float* outp = out + (size_t)(rowbase + rr) * H_;
#pragma unroll
        for (int i16 = 0; i16 < 4; i16++) {
            int i = i16 * 64 + ig * 4;
            const float* wh = w_out_high + i * 8;
            float4 s;
            s.x = b_out_high[i + 0]; s.y = b_out_high[i + 1];
            s.z = b_out_high[i + 2]; s.w = b_out_high[i + 3];
#pragma unroll
            for (int j = 0; j < 8; j++) {
                s.x += l[j] * wh[j];
                s.y += l[j] * wh[8 + j];
                s.z += l[j] * wh[16 + j];
                s.w += l[j] * wh[24 + j];
            }
            *(float4*)(outp + i) = s;
        }
    }
}

extern "C" void kernel_launch(void* const* d_in, const int* in_sizes, int n_in,
                              void* d_out, int out_size, void* d_ws, size_t ws_size,
                              hipStream_t stream) {
    const float* x          = (const float*)d_in[0];
    const float* w_qkv_low  = (const float*)d_in[1];
    const float* b_qkv_low  = (const float*)d_in[2];
    const float* w_qkv_high = (const float*)d_in[3];
    const float* b_qkv_high = (const float*)d_in[4];
    const float* w_out_low  = (const float*)d_in[5];
    const float* b_out_low  = (const float*)d_in[6];
    const float* w_out_high = (const float*)d_in[7];
    const float* b_out_high = (const float*)d_in[8];
    // d_in[9] adj_u, d_in[10] adj_v: unused (attn_reg_loss is the constant REGW/N)
    char* wsb = (char*)d_ws;
    float*    g_ql = (float*)(wsb);                           // 768 KB fp32 [24][8192]
    unsigned* kf_u = (unsigned*)(wsb + ((size_t)1 << 20));    // 4 MB  bf16 [4][8192][64]
    unsigned* v_u  = (unsigned*)(wsb + ((size_t)5 << 20));    // 4 MB
    float*    zg   = (float*)(wsb + ((size_t)9 << 20));       // 128 KB fp32 [8192][4]
    float*    kvp  = (float*)(wsb + ((size_t)10 << 20));      // 16 MB fp32 [1024][4096]
    float*    kvg  = (float*)(wsb + ((size_t)26 << 20));      // 256 KB fp32 [16][4096]
    float* out = (float*)d_out;

    ka_fused<<<512, 256, 0, stream>>>(x, w_qkv_low, b_qkv_low, w_qkv_high,
                                      b_qkv_high, g_ql, kf_u, v_u, zg);
    k2_kv<<<1024, 256, 0, stream>>>(kf_u, v_u, kvp);
    k2b_reduce<<<256, 256, 0, stream>>>(kvp, kvg, out);
    k4_out<<<512, 256, 0, stream>>>(g_ql, w_qkv_high, b_qkv_high, zg, kvg,
                                    w_out_low, b_out_low, w_out_high,
                                    b_out_high, out);
}